// Round 9
// baseline (213.232 us; speedup 1.0000x reference)
//
#include <hip/hip_runtime.h>
#include <hip/hip_bf16.h>
#include <cstdint>

// GAT 3-layer pipeline, MI355X. B=4, N=2048, Fin=128, nhid=64, H=8, emb=64, nclass=16.
// fp32 tensors; d_out = [image_feature (4*2048*64) | pre (4*16)] fp32.
// Round 9: attention keeps r5/r8 bf16 numerics (56 VGPR -> 8 waves/SIMD eligible) but
// blocks are now 256 threads / 4 waves sharing the SAME 32 rows, each wave a kb-quarter;
// LDS tree combine (2 sets, 20 KB). Grid 2048 blocks = 8 blocks/CU (was 2) — occupancy
// was the proven lever (r8), traffic per row unchanged (r7 trap avoided).

#define NN 2048

typedef float f32x4 __attribute__((ext_vector_type(4)));
typedef __bf16 bf16x8 __attribute__((ext_vector_type(8)));

__device__ __forceinline__ unsigned pkbf(float a, float b) {
  __hip_bfloat162 t = __float22bfloat162_rn(make_float2(a, b));
  unsigned r;
  __builtin_memcpy(&r, &t, 4);
  return r;
}

// ---------------- adj -> u16 mask plane (0xFFFF / 0) ----------------
__global__ __launch_bounds__(256) void build_plane_k(const int* __restrict__ adj,
                                                     unsigned short* __restrict__ plane) {
  const int i = blockIdx.x;
#pragma unroll
  for (int jt = 0; jt < NN / 256; ++jt) {
    const int j = jt * 256 + threadIdx.x;
    plane[(long)i * NN + j] = adj[(long)i * NN + j] > 0 ? 0xFFFFu : 0u;
  }
}

// ---------------- W (fp32 [K x 64] per instance) -> bf16 hi/lo B-frag planes --------
__global__ __launch_bounds__(256) void swizw_k(const float* __restrict__ W,
                                               __bf16* __restrict__ hi,
                                               __bf16* __restrict__ lo, int K) {
  const long inst = blockIdx.y;
  const float* w = W + inst * K * 64;
  __bf16* h = hi + inst * K * 64;
  __bf16* l = lo + inst * K * 64;
  for (int idx = blockIdx.x * 256 + threadIdx.x; idx < K * 64; idx += gridDim.x * 256) {
    const int k = idx >> 6, n = idx & 63;
    const float v = w[idx];
    const __bf16 vh = (__bf16)v;
    const __bf16 vl = (__bf16)(v - (float)vh);
    const int pos = ((k >> 5) * 4 + (n >> 4)) * 512 + (((k >> 3) & 3) * 16 + (n & 15)) * 8 + (k & 7);
    h[pos] = vh;
    l[pos] = vl;
  }
}

// ---------------- MFMA GEMM (M rows, N=64). 128 thr, 32 rows/block. ----------------
struct GemmLd {
  float4 a0, a1;
  bf16x8 bh[4], bl[4];
};

__global__ __launch_bounds__(128) void gemm_mfma_k(
    const float* __restrict__ Aall, const __bf16* __restrict__ WFhi,
    const __bf16* __restrict__ WFlo, const float* __restrict__ avecAll,
    __bf16* __restrict__ WhBAll, float* __restrict__ Eo, float* __restrict__ Go,
    float* __restrict__ Fo, float* __restrict__ Ho, float* __restrict__ pC,
    int K, int KS, long aStrideB) {
  const int p = blockIdx.y;
  const int ks = blockIdx.z;
  const float* A = Aall + (long)(p & 3) * aStrideB;
  const long wfOff = (long)(p >> 2) * K * 64;
  const bf16x8* BhF = (const bf16x8*)(WFhi + wfOff);
  const bf16x8* BlF = (const bf16x8*)(WFlo + wfOff);

  const int t = threadIdx.x, lane = t & 63, wave = t >> 6;
  const int quad = lane >> 4, lm = lane & 15;
  const int i0w = blockIdx.x * 32 + wave * 16;
  const float* Arow = A + (long)(i0w + lm) * K;
  const int kBeg = ks * (K / KS), kEnd = kBeg + K / KS;

  f32x4 acc[4];
#pragma unroll
  for (int nt = 0; nt < 4; ++nt) acc[nt] = (f32x4){0.f, 0.f, 0.f, 0.f};

  auto LOAD = [&](GemmLd& L, int k0) {
    L.a0 = *(const float4*)(Arow + k0 + quad * 8);
    L.a1 = *(const float4*)(Arow + k0 + quad * 8 + 4);
    const int bbase = (k0 >> 5) * 256 + lane;
#pragma unroll
    for (int nt = 0; nt < 4; ++nt) {
      L.bh[nt] = BhF[bbase + nt * 64];
      L.bl[nt] = BlF[bbase + nt * 64];
    }
  };
  auto STEP = [&](const GemmLd& L) {
    const float av8[8] = {L.a0.x, L.a0.y, L.a0.z, L.a0.w, L.a1.x, L.a1.y, L.a1.z, L.a1.w};
    bf16x8 ah, al;
#pragma unroll
    for (int j = 0; j < 8; ++j) {
      const __bf16 h = (__bf16)av8[j];
      ah[j] = h;
      al[j] = (__bf16)(av8[j] - (float)h);
    }
#pragma unroll
    for (int nt = 0; nt < 4; ++nt) {
      acc[nt] = __builtin_amdgcn_mfma_f32_16x16x32_bf16(ah, L.bh[nt], acc[nt], 0, 0, 0);
      acc[nt] = __builtin_amdgcn_mfma_f32_16x16x32_bf16(al, L.bh[nt], acc[nt], 0, 0, 0);
      acc[nt] = __builtin_amdgcn_mfma_f32_16x16x32_bf16(ah, L.bl[nt], acc[nt], 0, 0, 0);
    }
  };

  GemmLd La, Lb;
  LOAD(La, kBeg);
  for (int k0 = kBeg; k0 < kEnd; k0 += 64) {
    LOAD(Lb, k0 + 32);
    STEP(La);
    LOAD(La, (k0 + 64 < kEnd) ? k0 + 64 : kBeg);
    STEP(Lb);
  }

  if (KS > 1) {
    float* pc = pC + ((long)(p * KS + ks) * NN) * 64;
#pragma unroll
    for (int reg = 0; reg < 4; ++reg) {
      const int row = i0w + quad * 4 + reg;
#pragma unroll
      for (int nt = 0; nt < 4; ++nt) pc[(long)row * 64 + nt * 16 + lm] = acc[nt][reg];
    }
    return;
  }

  const float* av = avecAll + (long)(p >> 2) * 128;
  __bf16* WhB = WhBAll + (long)p * NN * 64;
  float* E = Eo + (long)p * NN;
  float* G = Go + (long)p * NN;
  float* F = Fo + (long)p * NN;
  float* Hh = Ho + (long)p * NN;

  float alo[4], ahi[4];
#pragma unroll
  for (int nt = 0; nt < 4; ++nt) {
    alo[nt] = av[nt * 16 + lm];
    ahi[nt] = av[64 + nt * 16 + lm];
  }
#pragma unroll
  for (int reg = 0; reg < 4; ++reg) {
    float es = 0.f, ed = 0.f;
#pragma unroll
    for (int nt = 0; nt < 4; ++nt) {
      es += acc[nt][reg] * alo[nt];
      ed += acc[nt][reg] * ahi[nt];
    }
#pragma unroll
    for (int m = 1; m < 16; m <<= 1) {
      es += __shfl_xor(es, m);
      ed += __shfl_xor(ed, m);
    }
    if (lm == 0) {
      const int r = i0w + quad * 4 + reg;
      E[r] = __expf(es);
      G[r] = __expf(0.2f * es);
      F[r] = __expf(ed);
      Hh[r] = __expf(0.2f * ed);
    }
  }

  const int r0 = i0w + quad * 4;
  const long base = ((long)(r0 >> 5) * 4) * 512 + (((r0 >> 3) & 3) * 16 + lm) * 8 + (r0 & 7);
#pragma unroll
  for (int nt = 0; nt < 4; ++nt) {
    const unsigned lo32 = pkbf(acc[nt][0], acc[nt][1]);
    const unsigned hi32 = pkbf(acc[nt][2], acc[nt][3]);
    *(uint2*)(WhB + base + nt * 512) = make_uint2(lo32, hi32);
  }
}

// ---------------- layer-2 GEMM epilogue: sum KS partials -> E/G/F/H + WhB bf16 ----
__global__ __launch_bounds__(256) void gemm_epi_k(
    const float* __restrict__ pC, const float* __restrict__ avec,
    __bf16* __restrict__ WhBAll, float* __restrict__ Eo, float* __restrict__ Go,
    float* __restrict__ Fo, float* __restrict__ Ho, int KS) {
  const int inst = blockIdx.y;
  const int t = threadIdx.x;
  const int row = blockIdx.x * 16 + (t >> 4);
  const int cg = t & 15;
  f32x4 c = (f32x4){0.f, 0.f, 0.f, 0.f};
  for (int ks = 0; ks < KS; ++ks)
    c += *(const f32x4*)(pC + (((long)(inst * KS + ks) * NN) + row) * 64 + cg * 4);
  float es = 0.f, ed = 0.f;
#pragma unroll
  for (int q = 0; q < 4; ++q) {
    const int n = cg * 4 + q;
    es += c[q] * avec[n];
    ed += c[q] * avec[64 + n];
  }
#pragma unroll
  for (int m = 1; m < 16; m <<= 1) {
    es += __shfl_xor(es, m);
    ed += __shfl_xor(ed, m);
  }
  if (cg == 0) {
    Eo[(long)inst * NN + row] = __expf(es);
    Go[(long)inst * NN + row] = __expf(0.2f * es);
    Fo[(long)inst * NN + row] = __expf(ed);
    Ho[(long)inst * NN + row] = __expf(0.2f * ed);
  }
  __bf16* WhB = WhBAll + (long)inst * NN * 64;
#pragma unroll
  for (int q = 0; q < 4; ++q) {
    const int n = cg * 4 + q;
    const int pos = ((row >> 5) * 4 + (n >> 4)) * 512 + (((row >> 3) & 3) * 16 + (n & 15)) * 8 + (row & 7);
    WhB[pos] = (__bf16)c[q];
  }
}

// ---------------- attention: P = mask & max(E*F, G*H), out = elu((P@WhB)/rowsum) ----
// 256 threads = 4 waves, ALL on the same 32 rows; wave w owns kb-quarter w of this js
// span. LDS tree combine: waves 2,3 -> LDS; waves 0,1 add; wave 1 -> LDS; wave 0 adds
// + epilogue. 20 KB LDS, lane-contiguous f32x4 (bank-optimal). r5/r8 bf16 numerics.
struct AttnLd {
  float4 Fa, Fc, Ha, Hc;
  uint4 m0, m1;
  bf16x8 b[4];
};

__global__ __launch_bounds__(256) void attn_k(
    const __bf16* __restrict__ WhBAll, const float* __restrict__ Eb,
    const float* __restrict__ Gb, const float* __restrict__ Fb,
    const float* __restrict__ Hb, const unsigned short* __restrict__ plane,
    float* __restrict__ out1, float* __restrict__ out2, int rowStride, long strideB,
    int jsCount, float* __restrict__ partAcc, float* __restrict__ partSum) {
  const int p = blockIdx.z;
  const int js = blockIdx.y;
  const bf16x8* bp = (const bf16x8*)(WhBAll + (long)p * NN * 64);
  const float* E = Eb + (long)p * NN;
  const float* G = Gb + (long)p * NN;
  const float* F = Fb + (long)p * NN;
  const float* Hv = Hb + (long)p * NN;
  const int t = threadIdx.x, lane = t & 63, wave = t >> 6;
  const int quad = lane >> 4, lm = lane & 15;
  const int i0 = blockIdx.x * 32;
  const int span = 64 / jsCount;              // kb per global js job
  const int qspan = span / 4;                 // kb per wave
  const int kbBeg = js * span + wave * qspan;
  const int kbEnd = kbBeg + qspan;

  const float E0 = E[i0 + lm], G0 = G[i0 + lm];
  const float E1 = E[i0 + 16 + lm], G1 = G[i0 + 16 + lm];
  const unsigned short* mp0 = plane + (long)(i0 + lm) * NN;
  const unsigned short* mp1 = plane + (long)(i0 + 16 + lm) * NN;

  bf16x8 ones;
#pragma unroll
  for (int j = 0; j < 8; ++j) ones[j] = (lm == 0) ? (__bf16)1.0f : (__bf16)0.0f;

  f32x4 acc0[4], acc1[4], sum0, sum1;
#pragma unroll
  for (int nt = 0; nt < 4; ++nt) {
    acc0[nt] = (f32x4){0.f, 0.f, 0.f, 0.f};
    acc1[nt] = (f32x4){0.f, 0.f, 0.f, 0.f};
  }
  sum0 = (f32x4){0.f, 0.f, 0.f, 0.f};
  sum1 = (f32x4){0.f, 0.f, 0.f, 0.f};

  auto LOAD = [&](AttnLd& L, int kb) {
    const int c0 = kb * 32 + quad * 8;
    L.Fa = *(const float4*)(F + c0);
    L.Fc = *(const float4*)(F + c0 + 4);
    L.Ha = *(const float4*)(Hv + c0);
    L.Hc = *(const float4*)(Hv + c0 + 4);
    L.m0 = *(const uint4*)(mp0 + c0);
    L.m1 = *(const uint4*)(mp1 + c0);
#pragma unroll
    for (int nt = 0; nt < 4; ++nt) L.b[nt] = bp[(kb * 4 + nt) * 64 + lane];
  };
  auto STEP = [&](const AttnLd& L) {
    const float Fv8[8] = {L.Fa.x, L.Fa.y, L.Fa.z, L.Fa.w, L.Fc.x, L.Fc.y, L.Fc.z, L.Fc.w};
    const float Hv8[8] = {L.Ha.x, L.Ha.y, L.Ha.z, L.Ha.w, L.Hc.x, L.Hc.y, L.Hc.z, L.Hc.w};
    union { uint4 u; bf16x8 v; } A0, A1;
    A0.u.x = pkbf(fmaxf(E0 * Fv8[0], G0 * Hv8[0]), fmaxf(E0 * Fv8[1], G0 * Hv8[1])) & L.m0.x;
    A0.u.y = pkbf(fmaxf(E0 * Fv8[2], G0 * Hv8[2]), fmaxf(E0 * Fv8[3], G0 * Hv8[3])) & L.m0.y;
    A0.u.z = pkbf(fmaxf(E0 * Fv8[4], G0 * Hv8[4]), fmaxf(E0 * Fv8[5], G0 * Hv8[5])) & L.m0.z;
    A0.u.w = pkbf(fmaxf(E0 * Fv8[6], G0 * Hv8[6]), fmaxf(E0 * Fv8[7], G0 * Hv8[7])) & L.m0.w;
    A1.u.x = pkbf(fmaxf(E1 * Fv8[0], G1 * Hv8[0]), fmaxf(E1 * Fv8[1], G1 * Hv8[1])) & L.m1.x;
    A1.u.y = pkbf(fmaxf(E1 * Fv8[2], G1 * Hv8[2]), fmaxf(E1 * Fv8[3], G1 * Hv8[3])) & L.m1.y;
    A1.u.z = pkbf(fmaxf(E1 * Fv8[4], G1 * Hv8[4]), fmaxf(E1 * Fv8[5], G1 * Hv8[5])) & L.m1.z;
    A1.u.w = pkbf(fmaxf(E1 * Fv8[6], G1 * Hv8[6]), fmaxf(E1 * Fv8[7], G1 * Hv8[7])) & L.m1.w;
#pragma unroll
    for (int nt = 0; nt < 4; ++nt) {
      acc0[nt] = __builtin_amdgcn_mfma_f32_16x16x32_bf16(A0.v, L.b[nt], acc0[nt], 0, 0, 0);
      acc1[nt] = __builtin_amdgcn_mfma_f32_16x16x32_bf16(A1.v, L.b[nt], acc1[nt], 0, 0, 0);
    }
    sum0 = __builtin_amdgcn_mfma_f32_16x16x32_bf16(A0.v, ones, sum0, 0, 0, 0);
    sum1 = __builtin_amdgcn_mfma_f32_16x16x32_bf16(A1.v, ones, sum1, 0, 0, 0);
  };

  AttnLd La, Lb;
  LOAD(La, kbBeg);
  for (int kb = kbBeg; kb < kbEnd; kb += 2) {
    LOAD(Lb, kb + 1);
    STEP(La);
    LOAD(La, (kb + 2 < kbEnd) ? kb + 2 : kbBeg);
    STEP(Lb);
  }

  // ---- LDS tree combine of the 4 kb-quarters (2 sets x 10 f32x4-frags x 64 lanes) ----
  __shared__ f32x4 cmb[2][10][64];  // 20 KB, lane-contiguous f32x4 (conflict-free b128)
  if (wave >= 2) {
    const int set = wave - 2;
#pragma unroll
    for (int nt = 0; nt < 4; ++nt) {
      cmb[set][nt][lane] = acc0[nt];
      cmb[set][4 + nt][lane] = acc1[nt];
    }
    cmb[set][8][lane] = sum0;
    cmb[set][9][lane] = sum1;
  }
  __syncthreads();
  if (wave < 2) {
    const int set = wave;  // wave0 <- set0 (wave2), wave1 <- set1 (wave3)
#pragma unroll
    for (int nt = 0; nt < 4; ++nt) {
      acc0[nt] += cmb[set][nt][lane];
      acc1[nt] += cmb[set][4 + nt][lane];
    }
    sum0 += cmb[set][8][lane];
    sum1 += cmb[set][9][lane];
    if (wave == 1) {  // wave1 writes its combined back to set1 (only it read set1)
#pragma unroll
      for (int nt = 0; nt < 4; ++nt) {
        cmb[1][nt][lane] = acc0[nt];
        cmb[1][4 + nt][lane] = acc1[nt];
      }
      cmb[1][8][lane] = sum0;
      cmb[1][9][lane] = sum1;
    }
  }
  __syncthreads();
  if (wave != 0) return;
#pragma unroll
  for (int nt = 0; nt < 4; ++nt) {
    acc0[nt] += cmb[1][nt][lane];
    acc1[nt] += cmb[1][4 + nt][lane];
  }
  sum0 += cmb[1][8][lane];
  sum1 += cmb[1][9][lane];

  if (jsCount == 1) {
#pragma unroll
    for (int g = 0; g < 2; ++g) {
      const f32x4* acc = g ? acc1 : acc0;
      const f32x4 sm = g ? sum1 : sum0;
#pragma unroll
      for (int reg = 0; reg < 4; ++reg) {
        const int row = i0 + g * 16 + quad * 4 + reg;
        const float ls = __shfl(sm[reg], quad * 16);
        const float il = ls > 0.f ? 1.f / ls : 0.f;
#pragma unroll
        for (int nt = 0; nt < 4; ++nt) {
          float v = acc[nt][reg] * il;
          v = v > 0.f ? v : expm1f(v);  // elu
          const long o = (long)(p & 3) * strideB + (long)row * rowStride + (p >> 2) * 64 + nt * 16 + lm;
          out1[o] = v;
          if (out2) out2[o] = v;
        }
      }
    }
  } else {
    float* pAcc = partAcc + ((long)p * jsCount + js) * NN * 64;
    float* pSum = partSum + ((long)p * jsCount + js) * NN;
#pragma unroll
    for (int g = 0; g < 2; ++g) {
      const f32x4* acc = g ? acc1 : acc0;
      const f32x4 sm = g ? sum1 : sum0;
#pragma unroll
      for (int reg = 0; reg < 4; ++reg) {
        const int row = i0 + g * 16 + quad * 4 + reg;
#pragma unroll
        for (int nt = 0; nt < 4; ++nt) pAcc[(long)row * 64 + nt * 16 + lm] = acc[nt][reg];
        if (lm == 0) pSum[row] = sm[reg];
      }
    }
  }
}

// ---------------- combine j-split partials: normalize + elu + dual write ----------------
__global__ __launch_bounds__(256) void combine_k(const float* __restrict__ partAcc,
                                                 const float* __restrict__ partSum,
                                                 float* __restrict__ img,
                                                 float* __restrict__ out, int JS) {
  const long idx = (long)blockIdx.x * 256 + threadIdx.x;
  const int cg = idx & 15;
  const int row = (int)((idx >> 4) & (NN - 1));
  const int inst = (int)(idx >> 15);
  f32x4 v = (f32x4){0.f, 0.f, 0.f, 0.f};
  float s = 0.f;
  for (int js = 0; js < JS; ++js) {
    const long b = ((long)inst * JS + js) * NN;
    v += *(const f32x4*)(partAcc + (b + row) * 64 + cg * 4);
    s += partSum[b + row];
  }
  const float il = s > 0.f ? 1.f / s : 0.f;
  f32x4 r;
#pragma unroll
  for (int q = 0; q < 4; ++q) {
    float x = v[q] * il;
    r[q] = x > 0.f ? x : expm1f(x);
  }
  const long o = ((long)inst * NN + row) * 64 + cg * 4;
  *(f32x4*)(img + o) = r;
  *(f32x4*)(out + o) = r;
}

// ---------------- layer-3 Wh3 = imgfeat @ W2 (K=64, Nc=16), fp32 ----------------
__global__ __launch_bounds__(256) void gemm16_k(const float* __restrict__ Aall,
                                                const float* __restrict__ Bw,
                                                float* __restrict__ Call) {
  const int bb = blockIdx.y;
  const float* A = Aall + (long)bb * NN * 64;
  float* C = Call + (long)bb * NN * 16;
  const int r0 = blockIdx.x * 16;
  const int t = threadIdx.x;
  __shared__ float As[16][65];
  __shared__ float Bs[64][16];
  const int c = t & 15, r = t >> 4;
#pragma unroll
  for (int q = 0; q < 4; ++q) {
    const int idx = q * 256 + t;
    As[idx >> 6][idx & 63] = A[(long)(r0 + (idx >> 6)) * 64 + (idx & 63)];
    Bs[idx >> 4][idx & 15] = Bw[idx];
  }
  __syncthreads();
  float acc = 0.f;
#pragma unroll 16
  for (int k = 0; k < 64; ++k) acc += As[r][k] * Bs[k][c];
  C[(long)(r0 + r) * 16 + c] = acc;
}

// ---------------- layer-3 finalize: only attention row 0 matters ----------------
__global__ __launch_bounds__(256) void layer3_k(const float* __restrict__ Wh3,
                                                const float* __restrict__ a2,
                                                const unsigned short* __restrict__ plane,
                                                float* __restrict__ outPre) {
  const int bb = blockIdx.x, t = threadIdx.x;
  const float* W = Wh3 + (long)bb * NN * 16;
  __shared__ float wsum[4];
  __shared__ float vacc[4][16];
  float alo[16], ahi[16];
#pragma unroll
  for (int c = 0; c < 16; ++c) {
    alo[c] = a2[c];
    ahi[c] = a2[16 + c];
  }
  float es = 0.f;
#pragma unroll
  for (int c = 0; c < 16; ++c) es += W[c] * alo[c];

  float lsum = 0.f;
  float acc[16];
#pragma unroll
  for (int c = 0; c < 16; ++c) acc[c] = 0.f;
  for (int j = t; j < NN; j += 256) {
    float ed = 0.f;
#pragma unroll
    for (int c = 0; c < 16; ++c) ed += W[(long)j * 16 + c] * ahi[c];
    float e = es + ed;
    e = fmaxf(e, 0.2f * e);
    const float pv = plane[j] ? __expf(e) : 0.f;
    lsum += pv;
#pragma unroll
    for (int c = 0; c < 16; ++c) acc[c] += pv * W[(long)j * 16 + c];
  }
#pragma unroll
  for (int off = 32; off > 0; off >>= 1) {
    lsum += __shfl_down(lsum, off);
#pragma unroll
    for (int c = 0; c < 16; ++c) acc[c] += __shfl_down(acc[c], off);
  }
  if ((t & 63) == 0) {
    wsum[t >> 6] = lsum;
#pragma unroll
    for (int c = 0; c < 16; ++c) vacc[t >> 6][c] = acc[c];
  }
  __syncthreads();
  if (t < 16) {
    const float a = vacc[0][t] + vacc[1][t] + vacc[2][t] + vacc[3][t];
    const float l = wsum[0] + wsum[1] + wsum[2] + wsum[3];
    float v = a / l;
    v = v > 0.f ? v : expm1f(v);
    outPre[bb * 16 + t] = v;
  }
}

// ---------------- host ----------------
extern "C" void kernel_launch(void* const* d_in, const int* in_sizes, int n_in,
                              void* d_out, int out_size, void* d_ws, size_t ws_size,
                              hipStream_t stream) {
  (void)in_sizes; (void)n_in; (void)out_size; (void)ws_size;
  constexpr int B = 4, N = NN, JS2 = 4, KS2 = 4;

  const float* slices = (const float*)d_in[0];
  const int* adj = (const int*)d_in[1];
  const float* Ws = (const float*)d_in[2];
  const float* As = (const float*)d_in[3];
  const float* W1 = (const float*)d_in[4];
  const float* a1 = (const float*)d_in[5];
  const float* W2 = (const float*)d_in[6];
  const float* a2 = (const float*)d_in[7];
  float* out = (float*)d_out;

  char* w = (char*)d_ws;
  size_t off = 0;
  auto alloc = [&](size_t bytes) {
    void* ptr = w + off;
    off += (bytes + 255) & ~(size_t)255;
    return ptr;
  };
  unsigned short* plane = (unsigned short*)alloc((size_t)N * N * 2);  // 8 MB
  __bf16* WsFh = (__bf16*)alloc((size_t)8 * 128 * 64 * 2);
  __bf16* WsFl = (__bf16*)alloc((size_t)8 * 128 * 64 * 2);
  __bf16* W1Fh = (__bf16*)alloc((size_t)512 * 64 * 2);
  __bf16* W1Fl = (__bf16*)alloc((size_t)512 * 64 * 2);
  __bf16* WhB1 = (__bf16*)alloc((size_t)32 * N * 64 * 2);  // 8 MB
  float* E1 = (float*)alloc((size_t)32 * N * 4);
  float* G1 = (float*)alloc((size_t)32 * N * 4);
  float* F1 = (float*)alloc((size_t)32 * N * 4);
  float* H1 = (float*)alloc((size_t)32 * N * 4);
  float* x = (float*)alloc((size_t)B * N * 512 * 4);  // 16 MB
  float* pC2 = (float*)alloc((size_t)B * KS2 * N * 64 * 4);  // 8 MB
  __bf16* WhB2 = (__bf16*)alloc((size_t)B * N * 64 * 2);
  float* E2 = (float*)alloc((size_t)B * N * 4);
  float* G2 = (float*)alloc((size_t)B * N * 4);
  float* F2 = (float*)alloc((size_t)B * N * 4);
  float* H2 = (float*)alloc((size_t)B * N * 4);
  float* img = (float*)alloc((size_t)B * N * 64 * 4);  // 2 MB
  float* Wh3 = (float*)alloc((size_t)B * N * 16 * 4);
  float* pAcc2 = (float*)alloc((size_t)B * JS2 * N * 64 * 4);  // 8 MB
  float* pSum2 = (float*)alloc((size_t)B * JS2 * N * 4);

  build_plane_k<<<dim3(N), dim3(256), 0, stream>>>(adj, plane);
  swizw_k<<<dim3(32, 8), dim3(256), 0, stream>>>(Ws, WsFh, WsFl, 128);
  swizw_k<<<dim3(128, 1), dim3(256), 0, stream>>>(W1, W1Fh, W1Fl, 512);

  // layer 1: fused-epilogue GEMM (KS=1) + attention (32-row blocks, kb-quarter waves)
  gemm_mfma_k<<<dim3(N / 32, 32, 1), dim3(128), 0, stream>>>(
      slices, WsFh, WsFl, As, WhB1, E1, G1, F1, H1, (float*)nullptr,
      128, 1, (long)N * 128);
  attn_k<<<dim3(N / 32, 1, 32), dim3(256), 0, stream>>>(
      WhB1, E1, G1, F1, H1, plane, x, (float*)nullptr, 512, (long)N * 512,
      1, (float*)nullptr, (float*)nullptr);

  // layer 2: K-split GEMM (KS=4) + epilogue + attention (JS=4 x kb-quarter) + combine
  gemm_mfma_k<<<dim3(N / 32, 4, KS2), dim3(128), 0, stream>>>(
      x, W1Fh, W1Fl, a1, (__bf16*)nullptr, (float*)nullptr, (float*)nullptr,
      (float*)nullptr, (float*)nullptr, pC2, 512, KS2, (long)N * 512);
  gemm_epi_k<<<dim3(N / 16, 4), dim3(256), 0, stream>>>(
      pC2, a1, WhB2, E2, G2, F2, H2, KS2);
  attn_k<<<dim3(N / 32, JS2, 4), dim3(256), 0, stream>>>(
      WhB2, E2, G2, F2, H2, plane, (float*)nullptr, (float*)nullptr, 64, (long)N * 64,
      JS2, pAcc2, pSum2);
  combine_k<<<dim3(B * N * 16 / 256), dim3(256), 0, stream>>>(pAcc2, pSum2, img, out, JS2);

  // layer 3
  gemm16_k<<<dim3(N / 16, B), dim3(256), 0, stream>>>(img, W2, Wh3);
  layer3_k<<<dim3(B), dim3(256), 0, stream>>>(Wh3, a2, plane, out + (size_t)B * N * 64);
}

// Round 10
// 191.970 us; speedup vs baseline: 1.1108x; 1.1108x over previous
//
#include <hip/hip_runtime.h>
#include <hip/hip_bf16.h>
#include <cstdint>

// GAT 3-layer pipeline, MI355X. B=4, N=2048, Fin=128, nhid=64, H=8, emb=64, nclass=16.
// fp32 tensors; d_out = [image_feature (4*2048*64) | pre (4*16)] fp32.
// Round 10: r8's proven attention structure (512 thr, internal kb-half split, depth-2,
// LDS combine) with fp16 P-gen (r6-proven numerics: packed mul/max halves VALU; smaller
// buffers than bf16 path). GEMMs keep bf16 hi/lo. Tail: fused prep kernel, and
// gemm16+layer3 replaced by j-split layer3a (on-the-fly Wh3) + layer3b reduce.

#define NN 2048

typedef float f32x4 __attribute__((ext_vector_type(4)));
typedef __bf16 bf16x8 __attribute__((ext_vector_type(8)));
typedef _Float16 f16;
typedef _Float16 f16x8 __attribute__((ext_vector_type(8)));

__device__ __forceinline__ unsigned pkbf(float a, float b) {
  __hip_bfloat162 t = __float22bfloat162_rn(make_float2(a, b));
  unsigned r;
  __builtin_memcpy(&r, &t, 4);
  return r;
}

// ---------------- fused prep: adj->plane, Ws->bf16 hi/lo frags, W1->bf16 hi/lo frags ----
__global__ __launch_bounds__(256) void prep_k(
    const int* __restrict__ adj, unsigned short* __restrict__ plane,
    const float* __restrict__ Ws, __bf16* __restrict__ WsFh, __bf16* __restrict__ WsFl,
    const float* __restrict__ W1, __bf16* __restrict__ W1Fh, __bf16* __restrict__ W1Fl) {
  const int bx = blockIdx.x, t = threadIdx.x;
  if (bx < 2048) {
    const long base = (long)bx * NN;
#pragma unroll
    for (int jt = 0; jt < 8; ++jt) {
      const int j = jt * 256 + t;
      plane[base + j] = adj[base + j] > 0 ? 0xFFFFu : 0u;
    }
  } else if (bx < 2304) {
    const int idx = (bx - 2048) * 256 + t;  // 8 inst x 8192
    const int inst = idx >> 13;
    const int rem = idx & 8191;
    const int k = rem >> 6, n = rem & 63;
    const float v = Ws[(long)inst * 8192 + rem];
    const __bf16 vh = (__bf16)v;
    const int pos = ((k >> 5) * 4 + (n >> 4)) * 512 + (((k >> 3) & 3) * 16 + (n & 15)) * 8 + (k & 7);
    WsFh[(long)inst * 8192 + pos] = vh;
    WsFl[(long)inst * 8192 + pos] = (__bf16)(v - (float)vh);
  } else {
    const int idx = (bx - 2304) * 256 + t;  // 512 x 64
    const int k = idx >> 6, n = idx & 63;
    const float v = W1[idx];
    const __bf16 vh = (__bf16)v;
    const int pos = ((k >> 5) * 4 + (n >> 4)) * 512 + (((k >> 3) & 3) * 16 + (n & 15)) * 8 + (k & 7);
    W1Fh[pos] = vh;
    W1Fl[pos] = (__bf16)(v - (float)vh);
  }
}

// ---------------- MFMA GEMM (M rows, N=64). 128 thr, 32 rows/block. ----------------
// KS==1: fused epilogue -> E/G fp32, F/H fp16, WhB fp16 frags. KS>1: fp32 partials.
struct GemmLd {
  float4 a0, a1;
  bf16x8 bh[4], bl[4];
};

__global__ __launch_bounds__(128) void gemm_mfma_k(
    const float* __restrict__ Aall, const __bf16* __restrict__ WFhi,
    const __bf16* __restrict__ WFlo, const float* __restrict__ avecAll,
    f16* __restrict__ WhBAll, float* __restrict__ Eo, float* __restrict__ Go,
    f16* __restrict__ Fo, f16* __restrict__ Ho, float* __restrict__ pC,
    int K, int KS, long aStrideB) {
  const int p = blockIdx.y;
  const int ks = blockIdx.z;
  const float* A = Aall + (long)(p & 3) * aStrideB;
  const long wfOff = (long)(p >> 2) * K * 64;
  const bf16x8* BhF = (const bf16x8*)(WFhi + wfOff);
  const bf16x8* BlF = (const bf16x8*)(WFlo + wfOff);

  const int t = threadIdx.x, lane = t & 63, wave = t >> 6;
  const int quad = lane >> 4, lm = lane & 15;
  const int i0w = blockIdx.x * 32 + wave * 16;
  const float* Arow = A + (long)(i0w + lm) * K;
  const int kBeg = ks * (K / KS), kEnd = kBeg + K / KS;

  f32x4 acc[4];
#pragma unroll
  for (int nt = 0; nt < 4; ++nt) acc[nt] = (f32x4){0.f, 0.f, 0.f, 0.f};

  auto LOAD = [&](GemmLd& L, int k0) {
    L.a0 = *(const float4*)(Arow + k0 + quad * 8);
    L.a1 = *(const float4*)(Arow + k0 + quad * 8 + 4);
    const int bbase = (k0 >> 5) * 256 + lane;
#pragma unroll
    for (int nt = 0; nt < 4; ++nt) {
      L.bh[nt] = BhF[bbase + nt * 64];
      L.bl[nt] = BlF[bbase + nt * 64];
    }
  };
  auto STEP = [&](const GemmLd& L) {
    const float av8[8] = {L.a0.x, L.a0.y, L.a0.z, L.a0.w, L.a1.x, L.a1.y, L.a1.z, L.a1.w};
    bf16x8 ah, al;
#pragma unroll
    for (int j = 0; j < 8; ++j) {
      const __bf16 h = (__bf16)av8[j];
      ah[j] = h;
      al[j] = (__bf16)(av8[j] - (float)h);
    }
#pragma unroll
    for (int nt = 0; nt < 4; ++nt) {
      acc[nt] = __builtin_amdgcn_mfma_f32_16x16x32_bf16(ah, L.bh[nt], acc[nt], 0, 0, 0);
      acc[nt] = __builtin_amdgcn_mfma_f32_16x16x32_bf16(al, L.bh[nt], acc[nt], 0, 0, 0);
      acc[nt] = __builtin_amdgcn_mfma_f32_16x16x32_bf16(ah, L.bl[nt], acc[nt], 0, 0, 0);
    }
  };

  GemmLd La, Lb;
  LOAD(La, kBeg);
  for (int k0 = kBeg; k0 < kEnd; k0 += 64) {
    LOAD(Lb, k0 + 32);
    STEP(La);
    LOAD(La, (k0 + 64 < kEnd) ? k0 + 64 : kBeg);
    STEP(Lb);
  }

  if (KS > 1) {
    float* pc = pC + ((long)(p * KS + ks) * NN) * 64;
#pragma unroll
    for (int reg = 0; reg < 4; ++reg) {
      const int row = i0w + quad * 4 + reg;
#pragma unroll
      for (int nt = 0; nt < 4; ++nt) pc[(long)row * 64 + nt * 16 + lm] = acc[nt][reg];
    }
    return;
  }

  const float* av = avecAll + (long)(p >> 2) * 128;
  f16* WhB = WhBAll + (long)p * NN * 64;
  float* E = Eo + (long)p * NN;
  float* G = Go + (long)p * NN;
  f16* F = Fo + (long)p * NN;
  f16* Hh = Ho + (long)p * NN;

  float alo[4], ahi[4];
#pragma unroll
  for (int nt = 0; nt < 4; ++nt) {
    alo[nt] = av[nt * 16 + lm];
    ahi[nt] = av[64 + nt * 16 + lm];
  }
#pragma unroll
  for (int reg = 0; reg < 4; ++reg) {
    float es = 0.f, ed = 0.f;
#pragma unroll
    for (int nt = 0; nt < 4; ++nt) {
      es += acc[nt][reg] * alo[nt];
      ed += acc[nt][reg] * ahi[nt];
    }
#pragma unroll
    for (int m = 1; m < 16; m <<= 1) {
      es += __shfl_xor(es, m);
      ed += __shfl_xor(ed, m);
    }
    if (lm == 0) {
      const int r = i0w + quad * 4 + reg;
      E[r] = __expf(es);
      G[r] = __expf(0.2f * es);
      F[r] = (f16)__expf(ed);
      Hh[r] = (f16)__expf(0.2f * ed);
    }
  }

  const int r0 = i0w + quad * 4;
  const long base = ((long)(r0 >> 5) * 4) * 512 + (((r0 >> 3) & 3) * 16 + lm) * 8 + (r0 & 7);
#pragma unroll
  for (int nt = 0; nt < 4; ++nt) {
    union { f16 h[4]; uint2 u; } pk;
#pragma unroll
    for (int q = 0; q < 4; ++q) pk.h[q] = (f16)acc[nt][q];
    *(uint2*)(WhB + base + nt * 512) = pk.u;
  }
}

// ---------------- layer-2 GEMM epilogue: sum KS partials -> E/G/F/H + WhB f16 ----
__global__ __launch_bounds__(256) void gemm_epi_k(
    const float* __restrict__ pC, const float* __restrict__ avec,
    f16* __restrict__ WhBAll, float* __restrict__ Eo, float* __restrict__ Go,
    f16* __restrict__ Fo, f16* __restrict__ Ho, int KS) {
  const int inst = blockIdx.y;
  const int t = threadIdx.x;
  const int row = blockIdx.x * 16 + (t >> 4);
  const int cg = t & 15;
  f32x4 c = (f32x4){0.f, 0.f, 0.f, 0.f};
  for (int ks = 0; ks < KS; ++ks)
    c += *(const f32x4*)(pC + (((long)(inst * KS + ks) * NN) + row) * 64 + cg * 4);
  float es = 0.f, ed = 0.f;
#pragma unroll
  for (int q = 0; q < 4; ++q) {
    const int n = cg * 4 + q;
    es += c[q] * avec[n];
    ed += c[q] * avec[64 + n];
  }
#pragma unroll
  for (int m = 1; m < 16; m <<= 1) {
    es += __shfl_xor(es, m);
    ed += __shfl_xor(ed, m);
  }
  if (cg == 0) {
    Eo[(long)inst * NN + row] = __expf(es);
    Go[(long)inst * NN + row] = __expf(0.2f * es);
    Fo[(long)inst * NN + row] = (f16)__expf(ed);
    Ho[(long)inst * NN + row] = (f16)__expf(0.2f * ed);
  }
  f16* WhB = WhBAll + (long)inst * NN * 64;
#pragma unroll
  for (int q = 0; q < 4; ++q) {
    const int n = cg * 4 + q;
    const int pos = ((row >> 5) * 4 + (n >> 4)) * 512 + (((row >> 3) & 3) * 16 + (n & 15)) * 8 + (row & 7);
    WhB[pos] = (f16)c[q];
  }
}

// ---------------- attention: P = mask & max(E*F, G*H) in fp16, f16 MFMA ----------------
// r8 structure: 512 threads = 8 waves. Waves 0-3: 128 rows x kb-half 0; waves 4-7: same
// rows, half 1. One LDS combine. 32 rows/wave, depth-2 ping-pong.
struct AttnLd {
  f16x8 F, H;
  uint4 m0, m1;
  f16x8 b[4];
};

__global__ __launch_bounds__(512) void attn_k(
    const f16* __restrict__ WhBAll, const float* __restrict__ Eb,
    const float* __restrict__ Gb, const f16* __restrict__ Fb,
    const f16* __restrict__ Hb, const unsigned short* __restrict__ plane,
    float* __restrict__ out1, float* __restrict__ out2, int rowStride, long strideB,
    int jsCount, float* __restrict__ partAcc, float* __restrict__ partSum) {
  const int p = blockIdx.z;
  const int js = blockIdx.y;
  const f16x8* bp = (const f16x8*)(WhBAll + (long)p * NN * 64);
  const float* E = Eb + (long)p * NN;
  const float* G = Gb + (long)p * NN;
  const f16* F = Fb + (long)p * NN;
  const f16* Hv = Hb + (long)p * NN;
  const int t = threadIdx.x, lane = t & 63, wave = t >> 6;
  const int rw = wave & 3;     // row-wave
  const int half = wave >> 2;  // kb half
  const int quad = lane >> 4, lm = lane & 15;
  const int i0 = blockIdx.x * 128 + rw * 32;
  const int span = 64 / jsCount;
  const int kbBeg = js * span + half * (span / 2);
  const int kbEnd = kbBeg + span / 2;

  const f16 e0 = (f16)E[i0 + lm], g0 = (f16)G[i0 + lm];
  const f16 e1 = (f16)E[i0 + 16 + lm], g1 = (f16)G[i0 + 16 + lm];
  f16x8 e0v, g0v, e1v, g1v;
#pragma unroll
  for (int j = 0; j < 8; ++j) { e0v[j] = e0; g0v[j] = g0; e1v[j] = e1; g1v[j] = g1; }
  const unsigned short* mp0 = plane + (long)(i0 + lm) * NN;
  const unsigned short* mp1 = plane + (long)(i0 + 16 + lm) * NN;

  f16x8 ones;
#pragma unroll
  for (int j = 0; j < 8; ++j) ones[j] = (lm == 0) ? (f16)1.0f : (f16)0.0f;

  f32x4 acc0[4], acc1[4], sum0, sum1;
#pragma unroll
  for (int nt = 0; nt < 4; ++nt) {
    acc0[nt] = (f32x4){0.f, 0.f, 0.f, 0.f};
    acc1[nt] = (f32x4){0.f, 0.f, 0.f, 0.f};
  }
  sum0 = (f32x4){0.f, 0.f, 0.f, 0.f};
  sum1 = (f32x4){0.f, 0.f, 0.f, 0.f};

  auto LOAD = [&](AttnLd& L, int kb) {
    const int c0 = kb * 32 + quad * 8;
    L.F = *(const f16x8*)(F + c0);
    L.H = *(const f16x8*)(Hv + c0);
    L.m0 = *(const uint4*)(mp0 + c0);
    L.m1 = *(const uint4*)(mp1 + c0);
#pragma unroll
    for (int nt = 0; nt < 4; ++nt) L.b[nt] = bp[(kb * 4 + nt) * 64 + lane];
  };
  auto STEP = [&](const AttnLd& L) {
    union { f16x8 v; uint4 u; } A0, A1;
    A0.v = __builtin_elementwise_max(e0v * L.F, g0v * L.H);
    A1.v = __builtin_elementwise_max(e1v * L.F, g1v * L.H);
    A0.u.x &= L.m0.x; A0.u.y &= L.m0.y; A0.u.z &= L.m0.z; A0.u.w &= L.m0.w;
    A1.u.x &= L.m1.x; A1.u.y &= L.m1.y; A1.u.z &= L.m1.z; A1.u.w &= L.m1.w;
#pragma unroll
    for (int nt = 0; nt < 4; ++nt) {
      acc0[nt] = __builtin_amdgcn_mfma_f32_16x16x32_f16(A0.v, L.b[nt], acc0[nt], 0, 0, 0);
      acc1[nt] = __builtin_amdgcn_mfma_f32_16x16x32_f16(A1.v, L.b[nt], acc1[nt], 0, 0, 0);
    }
    sum0 = __builtin_amdgcn_mfma_f32_16x16x32_f16(A0.v, ones, sum0, 0, 0, 0);
    sum1 = __builtin_amdgcn_mfma_f32_16x16x32_f16(A1.v, ones, sum1, 0, 0, 0);
  };

  AttnLd La, Lb;
  LOAD(La, kbBeg);
  for (int kb = kbBeg; kb < kbEnd; kb += 2) {
    LOAD(Lb, kb + 1);
    STEP(La);
    LOAD(La, (kb + 2 < kbEnd) ? kb + 2 : kbBeg);
    STEP(Lb);
  }

  // ---- combine the two kb-halves via LDS ----
  __shared__ float cmb[4 * 64 * 40];  // 40 KB
  if (half == 1) {
    float* dst = &cmb[(rw * 64 + lane) * 40];
#pragma unroll
    for (int nt = 0; nt < 4; ++nt) {
      *(f32x4*)(dst + nt * 4) = acc0[nt];
      *(f32x4*)(dst + 16 + nt * 4) = acc1[nt];
    }
    *(f32x4*)(dst + 32) = sum0;
    *(f32x4*)(dst + 36) = sum1;
  }
  __syncthreads();
  if (half == 1) return;
  {
    const float* src = &cmb[(rw * 64 + lane) * 40];
#pragma unroll
    for (int nt = 0; nt < 4; ++nt) {
      acc0[nt] += *(const f32x4*)(src + nt * 4);
      acc1[nt] += *(const f32x4*)(src + 16 + nt * 4);
    }
    sum0 += *(const f32x4*)(src + 32);
    sum1 += *(const f32x4*)(src + 36);
  }

  if (jsCount == 1) {
#pragma unroll
    for (int g = 0; g < 2; ++g) {
      const f32x4* acc = g ? acc1 : acc0;
      const f32x4 sm = g ? sum1 : sum0;
#pragma unroll
      for (int reg = 0; reg < 4; ++reg) {
        const int row = i0 + g * 16 + quad * 4 + reg;
        const float ls = __shfl(sm[reg], quad * 16);
        const float il = ls > 0.f ? 1.f / ls : 0.f;
#pragma unroll
        for (int nt = 0; nt < 4; ++nt) {
          float v = acc[nt][reg] * il;
          v = v > 0.f ? v : expm1f(v);  // elu
          const long o = (long)(p & 3) * strideB + (long)row * rowStride + (p >> 2) * 64 + nt * 16 + lm;
          out1[o] = v;
          if (out2) out2[o] = v;
        }
      }
    }
  } else {
    float* pAcc = partAcc + ((long)p * jsCount + js) * NN * 64;
    float* pSum = partSum + ((long)p * jsCount + js) * NN;
#pragma unroll
    for (int g = 0; g < 2; ++g) {
      const f32x4* acc = g ? acc1 : acc0;
      const f32x4 sm = g ? sum1 : sum0;
#pragma unroll
      for (int reg = 0; reg < 4; ++reg) {
        const int row = i0 + g * 16 + quad * 4 + reg;
#pragma unroll
        for (int nt = 0; nt < 4; ++nt) pAcc[(long)row * 64 + nt * 16 + lm] = acc[nt][reg];
        if (lm == 0) pSum[row] = sm[reg];
      }
    }
  }
}

// ---------------- combine j-split partials: normalize + elu + dual write ----------------
__global__ __launch_bounds__(256) void combine_k(const float* __restrict__ partAcc,
                                                 const float* __restrict__ partSum,
                                                 float* __restrict__ img,
                                                 float* __restrict__ out, int JS) {
  const long idx = (long)blockIdx.x * 256 + threadIdx.x;
  const int cg = idx & 15;
  const int row = (int)((idx >> 4) & (NN - 1));
  const int inst = (int)(idx >> 15);
  f32x4 v = (f32x4){0.f, 0.f, 0.f, 0.f};
  float s = 0.f;
  for (int js = 0; js < JS; ++js) {
    const long b = ((long)inst * JS + js) * NN;
    v += *(const f32x4*)(partAcc + (b + row) * 64 + cg * 4);
    s += partSum[b + row];
  }
  const float il = s > 0.f ? 1.f / s : 0.f;
  f32x4 r;
#pragma unroll
  for (int q = 0; q < 4; ++q) {
    float x = v[q] * il;
    r[q] = x > 0.f ? x : expm1f(x);
  }
  const long o = ((long)inst * NN + row) * 64 + cg * 4;
  *(f32x4*)(img + o) = r;
  *(f32x4*)(out + o) = r;
}

// ---------------- layer-3a: on-the-fly Wh3, j-split partials (grid B x 8) ----------------
// Each thread owns one j. es/ed via w2alo/w2ahi = W2 @ a2 halves (LDS).
__global__ __launch_bounds__(256) void layer3a_k(
    const float* __restrict__ img, const float* __restrict__ W2,
    const float* __restrict__ a2, const unsigned short* __restrict__ plane,
    float* __restrict__ pOut /* [B][8][17] */) {
  const int bb = blockIdx.x, chunk = blockIdx.y, t = threadIdx.x;
  const float* A = img + (long)bb * NN * 64;
  __shared__ float w2alo[64], w2ahi[64];
  __shared__ float W2s[64][17];
  __shared__ float redc[4][17];
  if (t < 64) {
    float sl = 0.f, sh = 0.f;
#pragma unroll
    for (int c = 0; c < 16; ++c) {
      const float wv = W2[t * 16 + c];
      W2s[t][c] = wv;
      sl += wv * a2[c];
      sh += wv * a2[16 + c];
    }
    w2alo[t] = sl;
    w2ahi[t] = sh;
  }
  __syncthreads();

  // es = dot(img[bb,0,:], w2alo) (redundant per thread, broadcast loads)
  float es = 0.f;
#pragma unroll 16
  for (int k = 0; k < 64; ++k) es += A[k] * w2alo[k];

  const int j = chunk * 256 + t;
  float arow[64];
#pragma unroll
  for (int q = 0; q < 16; ++q) *(f32x4*)(arow + q * 4) = *(const f32x4*)(A + (long)j * 64 + q * 4);
  float ed = 0.f;
#pragma unroll
  for (int k = 0; k < 64; ++k) ed += arow[k] * w2ahi[k];
  float e = es + ed;
  e = fmaxf(e, 0.2f * e);
  const float pv = plane[j] ? __expf(e) : 0.f;

  float acc[16];
#pragma unroll
  for (int c = 0; c < 16; ++c) {
    float wh = 0.f;
#pragma unroll
    for (int k = 0; k < 64; ++k) wh += arow[k] * W2s[k][c];
    acc[c] = pv * wh;
  }
  float lsum = pv;

  // reduce 256 threads -> 17 values
#pragma unroll
  for (int off = 32; off > 0; off >>= 1) {
    lsum += __shfl_down(lsum, off);
#pragma unroll
    for (int c = 0; c < 16; ++c) acc[c] += __shfl_down(acc[c], off);
  }
  if ((t & 63) == 0) {
    const int wv = t >> 6;
#pragma unroll
    for (int c = 0; c < 16; ++c) redc[wv][c] = acc[c];
    redc[wv][16] = lsum;
  }
  __syncthreads();
  if (t < 17) {
    pOut[((long)bb * 8 + chunk) * 17 + t] =
        redc[0][t] + redc[1][t] + redc[2][t] + redc[3][t];
  }
}

// ---------------- layer-3b: sum 8 chunks, normalize + elu ----------------
__global__ __launch_bounds__(64) void layer3b_k(const float* __restrict__ pOut,
                                                float* __restrict__ outPre) {
  const int t = threadIdx.x;
  if (t >= 64) return;
  const int bb = t >> 4, c = t & 15;
  float a = 0.f, l = 0.f;
#pragma unroll
  for (int ch = 0; ch < 8; ++ch) {
    a += pOut[((long)bb * 8 + ch) * 17 + c];
    l += pOut[((long)bb * 8 + ch) * 17 + 16];
  }
  float v = a / l;
  v = v > 0.f ? v : expm1f(v);
  outPre[bb * 16 + c] = v;
}

// ---------------- host ----------------
extern "C" void kernel_launch(void* const* d_in, const int* in_sizes, int n_in,
                              void* d_out, int out_size, void* d_ws, size_t ws_size,
                              hipStream_t stream) {
  (void)in_sizes; (void)n_in; (void)out_size; (void)ws_size;
  constexpr int B = 4, N = NN, JS2 = 4, KS2 = 4;

  const float* slices = (const float*)d_in[0];
  const int* adj = (const int*)d_in[1];
  const float* Ws = (const float*)d_in[2];
  const float* As = (const float*)d_in[3];
  const float* W1 = (const float*)d_in[4];
  const float* a1 = (const float*)d_in[5];
  const float* W2 = (const float*)d_in[6];
  const float* a2 = (const float*)d_in[7];
  float* out = (float*)d_out;

  char* w = (char*)d_ws;
  size_t off = 0;
  auto alloc = [&](size_t bytes) {
    void* ptr = w + off;
    off += (bytes + 255) & ~(size_t)255;
    return ptr;
  };
  unsigned short* plane = (unsigned short*)alloc((size_t)N * N * 2);  // 8 MB
  __bf16* WsFh = (__bf16*)alloc((size_t)8 * 128 * 64 * 2);
  __bf16* WsFl = (__bf16*)alloc((size_t)8 * 128 * 64 * 2);
  __bf16* W1Fh = (__bf16*)alloc((size_t)512 * 64 * 2);
  __bf16* W1Fl = (__bf16*)alloc((size_t)512 * 64 * 2);
  f16* WhB1 = (f16*)alloc((size_t)32 * N * 64 * 2);  // 8 MB
  float* E1 = (float*)alloc((size_t)32 * N * 4);
  float* G1 = (float*)alloc((size_t)32 * N * 4);
  f16* F1 = (f16*)alloc((size_t)32 * N * 2);
  f16* H1 = (f16*)alloc((size_t)32 * N * 2);
  float* x = (float*)alloc((size_t)B * N * 512 * 4);  // 16 MB
  float* pC2 = (float*)alloc((size_t)B * KS2 * N * 64 * 4);  // 8 MB
  f16* WhB2 = (f16*)alloc((size_t)B * N * 64 * 2);
  float* E2 = (float*)alloc((size_t)B * N * 4);
  float* G2 = (float*)alloc((size_t)B * N * 4);
  f16* F2 = (f16*)alloc((size_t)B * N * 2);
  f16* H2 = (f16*)alloc((size_t)B * N * 2);
  float* img = (float*)alloc((size_t)B * N * 64 * 4);  // 2 MB
  float* pAcc2 = (float*)alloc((size_t)B * JS2 * N * 64 * 4);  // 8 MB
  float* pSum2 = (float*)alloc((size_t)B * JS2 * N * 4);
  float* pL3 = (float*)alloc((size_t)B * 8 * 17 * 4);

  prep_k<<<dim3(2432), dim3(256), 0, stream>>>(adj, plane, Ws, WsFh, WsFl, W1, W1Fh, W1Fl);

  // layer 1: fused-epilogue GEMM (KS=1) + attention (r8 structure, fp16 P-gen)
  gemm_mfma_k<<<dim3(N / 32, 32, 1), dim3(128), 0, stream>>>(
      slices, WsFh, WsFl, As, WhB1, E1, G1, F1, H1, (float*)nullptr,
      128, 1, (long)N * 128);
  attn_k<<<dim3(N / 128, 1, 32), dim3(512), 0, stream>>>(
      WhB1, E1, G1, F1, H1, plane, x, (float*)nullptr, 512, (long)N * 512,
      1, (float*)nullptr, (float*)nullptr);

  // layer 2: K-split GEMM (KS=4) + epilogue + attention (JS=4 x internal 2) + combine
  gemm_mfma_k<<<dim3(N / 32, 4, KS2), dim3(128), 0, stream>>>(
      x, W1Fh, W1Fl, a1, (f16*)nullptr, (float*)nullptr, (float*)nullptr,
      (f16*)nullptr, (f16*)nullptr, pC2, 512, KS2, (long)N * 512);
  gemm_epi_k<<<dim3(N / 16, 4), dim3(256), 0, stream>>>(
      pC2, a1, WhB2, E2, G2, F2, H2, KS2);
  attn_k<<<dim3(N / 128, JS2, 4), dim3(512), 0, stream>>>(
      WhB2, E2, G2, F2, H2, plane, (float*)nullptr, (float*)nullptr, 64, (long)N * 64,
      JS2, pAcc2, pSum2);
  combine_k<<<dim3(B * N * 16 / 256), dim3(256), 0, stream>>>(pAcc2, pSum2, img, out, JS2);

  // layer 3: fused on-the-fly Wh3 with j-split + tiny reduce
  layer3a_k<<<dim3(B, 8), dim3(256), 0, stream>>>(img, W2, a2, plane, pL3);
  layer3b_k<<<dim3(1), dim3(64), 0, stream>>>(pL3, out + (size_t)B * N * 64);
}

// Round 11
// 165.039 us; speedup vs baseline: 1.2920x; 1.1632x over previous
//
#include <hip/hip_runtime.h>
#include <hip/hip_bf16.h>
#include <cstdint>

// GAT 3-layer pipeline, MI355X. B=4, N=2048, Fin=128, nhid=64, H=8, emb=64, nclass=16.
// fp32 tensors; d_out = [image_feature (4*2048*64) | pre (4*16)] fp32.
// Round 11: attention rebuilt m97-style — B-tiles + mask-tiles staged ONCE per block via
// global_load_lds (double-buffered, 1 barrier/iter), consumed by all row-waves via
// ds_read_b128. Diagnosis: r5-r10 plateau (72-77us, all pipes <40%) was L1-fill-bandwidth
// on 4x-redundant B reads + mask bytes. Masks now u8 0xFF/0 plane in kb-tiled layout
// (half bytes, stageable), expanded with v_perm_b32. fp16 P-gen + f16 MFMA kept.

#define NN 2048

typedef float f32x4 __attribute__((ext_vector_type(4)));
typedef __bf16 bf16x8 __attribute__((ext_vector_type(8)));
typedef _Float16 f16;
typedef _Float16 f16x8 __attribute__((ext_vector_type(8)));

__device__ __forceinline__ void gll16(const void* g, void* l) {
  __builtin_amdgcn_global_load_lds(
      (const __attribute__((address_space(1))) unsigned int*)g,
      (__attribute__((address_space(3))) unsigned int*)l, 16, 0, 0);
}

// ---------------- fused prep: adj->u8 kb-tiled plane, Ws/W1 -> bf16 hi/lo frags ----
// pm layout: [kb(64)][i(2048)][jb(32)] u8 (0xFF if edge) — 4 MB, tiles contiguous.
__global__ __launch_bounds__(256) void prep_k(
    const int* __restrict__ adj, unsigned char* __restrict__ pm,
    const float* __restrict__ Ws, __bf16* __restrict__ WsFh, __bf16* __restrict__ WsFl,
    const float* __restrict__ W1, __bf16* __restrict__ W1Fh, __bf16* __restrict__ W1Fl) {
  const int bx = blockIdx.x, t = threadIdx.x;
  if (bx < 2048) {
    const int i = bx;
#pragma unroll
    for (int jt = 0; jt < 8; ++jt) {
      const int j = jt * 256 + t;
      pm[((long)(j >> 5) << 16) + i * 32 + (j & 31)] =
          adj[(long)i * NN + j] > 0 ? 0xFFu : 0u;
    }
  } else if (bx < 2304) {
    const int idx = (bx - 2048) * 256 + t;  // 8 inst x 8192
    const int inst = idx >> 13;
    const int rem = idx & 8191;
    const int k = rem >> 6, n = rem & 63;
    const float v = Ws[(long)inst * 8192 + rem];
    const __bf16 vh = (__bf16)v;
    const int pos = ((k >> 5) * 4 + (n >> 4)) * 512 + (((k >> 3) & 3) * 16 + (n & 15)) * 8 + (k & 7);
    WsFh[(long)inst * 8192 + pos] = vh;
    WsFl[(long)inst * 8192 + pos] = (__bf16)(v - (float)vh);
  } else {
    const int idx = (bx - 2304) * 256 + t;  // 512 x 64
    const int k = idx >> 6, n = idx & 63;
    const float v = W1[idx];
    const __bf16 vh = (__bf16)v;
    const int pos = ((k >> 5) * 4 + (n >> 4)) * 512 + (((k >> 3) & 3) * 16 + (n & 15)) * 8 + (k & 7);
    W1Fh[pos] = vh;
    W1Fl[pos] = (__bf16)(v - (float)vh);
  }
}

// ---------------- MFMA GEMM (M rows, N=64). 128 thr, 32 rows/block. ----------------
struct GemmLd {
  float4 a0, a1;
  bf16x8 bh[4], bl[4];
};

__global__ __launch_bounds__(128) void gemm_mfma_k(
    const float* __restrict__ Aall, const __bf16* __restrict__ WFhi,
    const __bf16* __restrict__ WFlo, const float* __restrict__ avecAll,
    f16* __restrict__ WhBAll, float* __restrict__ Eo, float* __restrict__ Go,
    f16* __restrict__ Fo, f16* __restrict__ Ho, float* __restrict__ pC,
    int K, int KS, long aStrideB) {
  const int p = blockIdx.y;
  const int ks = blockIdx.z;
  const float* A = Aall + (long)(p & 3) * aStrideB;
  const long wfOff = (long)(p >> 2) * K * 64;
  const bf16x8* BhF = (const bf16x8*)(WFhi + wfOff);
  const bf16x8* BlF = (const bf16x8*)(WFlo + wfOff);

  const int t = threadIdx.x, lane = t & 63, wave = t >> 6;
  const int quad = lane >> 4, lm = lane & 15;
  const int i0w = blockIdx.x * 32 + wave * 16;
  const float* Arow = A + (long)(i0w + lm) * K;
  const int kBeg = ks * (K / KS), kEnd = kBeg + K / KS;

  f32x4 acc[4];
#pragma unroll
  for (int nt = 0; nt < 4; ++nt) acc[nt] = (f32x4){0.f, 0.f, 0.f, 0.f};

  auto LOAD = [&](GemmLd& L, int k0) {
    L.a0 = *(const float4*)(Arow + k0 + quad * 8);
    L.a1 = *(const float4*)(Arow + k0 + quad * 8 + 4);
    const int bbase = (k0 >> 5) * 256 + lane;
#pragma unroll
    for (int nt = 0; nt < 4; ++nt) {
      L.bh[nt] = BhF[bbase + nt * 64];
      L.bl[nt] = BlF[bbase + nt * 64];
    }
  };
  auto STEP = [&](const GemmLd& L) {
    const float av8[8] = {L.a0.x, L.a0.y, L.a0.z, L.a0.w, L.a1.x, L.a1.y, L.a1.z, L.a1.w};
    bf16x8 ah, al;
#pragma unroll
    for (int j = 0; j < 8; ++j) {
      const __bf16 h = (__bf16)av8[j];
      ah[j] = h;
      al[j] = (__bf16)(av8[j] - (float)h);
    }
#pragma unroll
    for (int nt = 0; nt < 4; ++nt) {
      acc[nt] = __builtin_amdgcn_mfma_f32_16x16x32_bf16(ah, L.bh[nt], acc[nt], 0, 0, 0);
      acc[nt] = __builtin_amdgcn_mfma_f32_16x16x32_bf16(al, L.bh[nt], acc[nt], 0, 0, 0);
      acc[nt] = __builtin_amdgcn_mfma_f32_16x16x32_bf16(ah, L.bl[nt], acc[nt], 0, 0, 0);
    }
  };

  GemmLd La, Lb;
  LOAD(La, kBeg);
  for (int k0 = kBeg; k0 < kEnd; k0 += 64) {
    LOAD(Lb, k0 + 32);
    STEP(La);
    LOAD(La, (k0 + 64 < kEnd) ? k0 + 64 : kBeg);
    STEP(Lb);
  }

  if (KS > 1) {
    float* pc = pC + ((long)(p * KS + ks) * NN) * 64;
#pragma unroll
    for (int reg = 0; reg < 4; ++reg) {
      const int row = i0w + quad * 4 + reg;
#pragma unroll
      for (int nt = 0; nt < 4; ++nt) pc[(long)row * 64 + nt * 16 + lm] = acc[nt][reg];
    }
    return;
  }

  const float* av = avecAll + (long)(p >> 2) * 128;
  f16* WhB = WhBAll + (long)p * NN * 64;
  float* E = Eo + (long)p * NN;
  float* G = Go + (long)p * NN;
  f16* F = Fo + (long)p * NN;
  f16* Hh = Ho + (long)p * NN;

  float alo[4], ahi[4];
#pragma unroll
  for (int nt = 0; nt < 4; ++nt) {
    alo[nt] = av[nt * 16 + lm];
    ahi[nt] = av[64 + nt * 16 + lm];
  }
#pragma unroll
  for (int reg = 0; reg < 4; ++reg) {
    float es = 0.f, ed = 0.f;
#pragma unroll
    for (int nt = 0; nt < 4; ++nt) {
      es += acc[nt][reg] * alo[nt];
      ed += acc[nt][reg] * ahi[nt];
    }
#pragma unroll
    for (int m = 1; m < 16; m <<= 1) {
      es += __shfl_xor(es, m);
      ed += __shfl_xor(ed, m);
    }
    if (lm == 0) {
      const int r = i0w + quad * 4 + reg;
      E[r] = __expf(es);
      G[r] = __expf(0.2f * es);
      F[r] = (f16)__expf(ed);
      Hh[r] = (f16)__expf(0.2f * ed);
    }
  }

  const int r0 = i0w + quad * 4;
  const long base = ((long)(r0 >> 5) * 4) * 512 + (((r0 >> 3) & 3) * 16 + lm) * 8 + (r0 & 7);
#pragma unroll
  for (int nt = 0; nt < 4; ++nt) {
    union { f16 h[4]; uint2 u; } pk;
#pragma unroll
    for (int q = 0; q < 4; ++q) pk.h[q] = (f16)acc[nt][q];
    *(uint2*)(WhB + base + nt * 512) = pk.u;
  }
}

// ---------------- layer-2 GEMM epilogue: sum KS partials -> E/G/F/H + WhB f16 ----
__global__ __launch_bounds__(256) void gemm_epi_k(
    const float* __restrict__ pC, const float* __restrict__ avec,
    f16* __restrict__ WhBAll, float* __restrict__ Eo, float* __restrict__ Go,
    f16* __restrict__ Fo, f16* __restrict__ Ho, int KS) {
  const int inst = blockIdx.y;
  const int t = threadIdx.x;
  const int row = blockIdx.x * 16 + (t >> 4);
  const int cg = t & 15;
  f32x4 c = (f32x4){0.f, 0.f, 0.f, 0.f};
  for (int ks = 0; ks < KS; ++ks)
    c += *(const f32x4*)(pC + (((long)(inst * KS + ks) * NN) + row) * 64 + cg * 4);
  float es = 0.f, ed = 0.f;
#pragma unroll
  for (int q = 0; q < 4; ++q) {
    const int n = cg * 4 + q;
    es += c[q] * avec[n];
    ed += c[q] * avec[64 + n];
  }
#pragma unroll
  for (int m = 1; m < 16; m <<= 1) {
    es += __shfl_xor(es, m);
    ed += __shfl_xor(ed, m);
  }
  if (cg == 0) {
    Eo[(long)inst * NN + row] = __expf(es);
    Go[(long)inst * NN + row] = __expf(0.2f * es);
    Fo[(long)inst * NN + row] = (f16)__expf(ed);
    Ho[(long)inst * NN + row] = (f16)__expf(0.2f * ed);
  }
  f16* WhB = WhBAll + (long)inst * NN * 64;
#pragma unroll
  for (int q = 0; q < 4; ++q) {
    const int n = cg * 4 + q;
    const int pos = ((row >> 5) * 4 + (n >> 4)) * 512 + (((row >> 3) & 3) * 16 + (n & 15)) * 8 + (row & 7);
    WhB[pos] = (f16)c[q];
  }
}

// ---------------- attention: LDS-staged B/mask tiles, fp16 P-gen, f16 MFMA ----------
// 512 thr = 8 waves: rw = wave&3 (32 rows each, block = 128 rows), half = wave>>2
// (kb-half). Wave rw==0 of each half stages B (4KB) + mask (4KB) tiles for its half via
// global_load_lds, double-buffered; 1 __syncthreads per iteration; row-waves ds_read.
__global__ __launch_bounds__(512) void attn_k(
    const f16* __restrict__ WhBAll, const float* __restrict__ Eb,
    const float* __restrict__ Gb, const f16* __restrict__ Fb,
    const f16* __restrict__ Hb, const unsigned char* __restrict__ pm,
    float* __restrict__ out1, float* __restrict__ out2, int rowStride, long strideB,
    int jsCount, float* __restrict__ partAcc, float* __restrict__ partSum) {
  const int p = blockIdx.z;
  const int js = blockIdx.y;
  const f16* WhB = WhBAll + (long)p * NN * 64;
  const float* E = Eb + (long)p * NN;
  const float* G = Gb + (long)p * NN;
  const f16* F = Fb + (long)p * NN;
  const f16* Hv = Hb + (long)p * NN;
  const int t = threadIdx.x, lane = t & 63, wave = t >> 6;
  const int rw = wave & 3, half = wave >> 2;
  const int quad = lane >> 4, lm = lane & 15;
  const int i0 = blockIdx.x * 128;
  const int rbase = rw * 32;
  const int span = 64 / jsCount;
  const int nIter = span / 2;
  const int kbBeg = js * span + half * nIter;

  // LDS pool: [0,4K) F, [4K,8K) H, [8K,40K) rings (half*16K + slot*8K: B 4K | M 4K).
  // Combine phase overlays the whole pool (40 KB).
  __shared__ __align__(16) char pool[40960];
  f16* Fs = (f16*)pool;
  f16* Hs = (f16*)(pool + 4096);
  char* ring = pool + 8192 + half * 16384;

  const int r0g = i0 + rbase + lm, r1g = i0 + rbase + 16 + lm;
  const f16 e0 = (f16)E[r0g], g0 = (f16)G[r0g];
  const f16 e1 = (f16)E[r1g], g1 = (f16)G[r1g];
  f16x8 e0v, g0v, e1v, g1v;
#pragma unroll
  for (int j = 0; j < 8; ++j) { e0v[j] = e0; g0v[j] = g0; e1v[j] = e1; g1v[j] = g1; }

  f16x8 ones;
#pragma unroll
  for (int j = 0; j < 8; ++j) ones[j] = (lm == 0) ? (f16)1.0f : (f16)0.0f;

  // prologue staging
  if (wave == 0) {
#pragma unroll
    for (int q = 0; q < 4; ++q) gll16((const char*)F + q * 1024 + lane * 16, pool + q * 1024);
#pragma unroll
    for (int q = 0; q < 4; ++q) gll16((const char*)Hv + q * 1024 + lane * 16, pool + 4096 + q * 1024);
  }
  if (rw == 0) {
    const char* gB = (const char*)WhB + (long)kbBeg * 4096;
    const unsigned char* gM = pm + ((long)kbBeg << 16) + i0 * 32;
#pragma unroll
    for (int q = 0; q < 4; ++q) gll16(gB + q * 1024 + lane * 16, ring + q * 1024);
#pragma unroll
    for (int q = 0; q < 4; ++q) gll16(gM + q * 1024 + lane * 16, ring + 4096 + q * 1024);
  }
  __syncthreads();

  f32x4 acc0[4], acc1[4], sum0, sum1;
#pragma unroll
  for (int nt = 0; nt < 4; ++nt) {
    acc0[nt] = (f32x4){0.f, 0.f, 0.f, 0.f};
    acc1[nt] = (f32x4){0.f, 0.f, 0.f, 0.f};
  }
  sum0 = (f32x4){0.f, 0.f, 0.f, 0.f};
  sum1 = (f32x4){0.f, 0.f, 0.f, 0.f};

  for (int i = 0; i < nIter; ++i) {
    const int kb = kbBeg + i;
    if (rw == 0 && i + 1 < nIter) {  // prefetch next tiles into other slot
      char* dst = ring + ((i + 1) & 1) * 8192;
      const char* gB = (const char*)WhB + (long)(kb + 1) * 4096;
      const unsigned char* gM = pm + ((long)(kb + 1) << 16) + i0 * 32;
#pragma unroll
      for (int q = 0; q < 4; ++q) gll16(gB + q * 1024 + lane * 16, dst + q * 1024);
#pragma unroll
      for (int q = 0; q < 4; ++q) gll16(gM + q * 1024 + lane * 16, dst + 4096 + q * 1024);
    }
    const char* slot = ring + (i & 1) * 8192;
    const f16x8 F8 = *(const f16x8*)(Fs + kb * 32 + quad * 8);
    const f16x8 H8 = *(const f16x8*)(Hs + kb * 32 + quad * 8);
    const uint2 m0 = *(const uint2*)(slot + 4096 + (rbase + lm) * 32 + quad * 8);
    const uint2 m1 = *(const uint2*)(slot + 4096 + (rbase + 16 + lm) * 32 + quad * 8);

    union { f16x8 v; uint4 u; } A0, A1;
    A0.v = __builtin_elementwise_max(e0v * F8, g0v * H8);
    A1.v = __builtin_elementwise_max(e1v * F8, g1v * H8);
    A0.u.x &= __builtin_amdgcn_perm(0u, m0.x, 0x01010000u);
    A0.u.y &= __builtin_amdgcn_perm(0u, m0.x, 0x03030202u);
    A0.u.z &= __builtin_amdgcn_perm(0u, m0.y, 0x01010000u);
    A0.u.w &= __builtin_amdgcn_perm(0u, m0.y, 0x03030202u);
    A1.u.x &= __builtin_amdgcn_perm(0u, m1.x, 0x01010000u);
    A1.u.y &= __builtin_amdgcn_perm(0u, m1.x, 0x03030202u);
    A1.u.z &= __builtin_amdgcn_perm(0u, m1.y, 0x01010000u);
    A1.u.w &= __builtin_amdgcn_perm(0u, m1.y, 0x03030202u);

#pragma unroll
    for (int nt = 0; nt < 4; ++nt) {
      const f16x8 bfr = *(const f16x8*)(slot + (nt * 64 + lane) * 16);
      acc0[nt] = __builtin_amdgcn_mfma_f32_16x16x32_f16(A0.v, bfr, acc0[nt], 0, 0, 0);
      acc1[nt] = __builtin_amdgcn_mfma_f32_16x16x32_f16(A1.v, bfr, acc1[nt], 0, 0, 0);
    }
    sum0 = __builtin_amdgcn_mfma_f32_16x16x32_f16(A0.v, ones, sum0, 0, 0, 0);
    sum1 = __builtin_amdgcn_mfma_f32_16x16x32_f16(A1.v, ones, sum1, 0, 0, 0);
    __syncthreads();
  }

  // ---- combine the two kb-halves via LDS (overlay pool) ----
  float* cmb = (float*)pool;
  if (half == 1) {
    float* dst = &cmb[(rw * 64 + lane) * 40];
#pragma unroll
    for (int nt = 0; nt < 4; ++nt) {
      *(f32x4*)(dst + nt * 4) = acc0[nt];
      *(f32x4*)(dst + 16 + nt * 4) = acc1[nt];
    }
    *(f32x4*)(dst + 32) = sum0;
    *(f32x4*)(dst + 36) = sum1;
  }
  __syncthreads();
  if (half == 1) return;
  {
    const float* src = &cmb[(rw * 64 + lane) * 40];
#pragma unroll
    for (int nt = 0; nt < 4; ++nt) {
      acc0[nt] += *(const f32x4*)(src + nt * 4);
      acc1[nt] += *(const f32x4*)(src + 16 + nt * 4);
    }
    sum0 += *(const f32x4*)(src + 32);
    sum1 += *(const f32x4*)(src + 36);
  }

  if (jsCount == 1) {
#pragma unroll
    for (int g = 0; g < 2; ++g) {
      const f32x4* acc = g ? acc1 : acc0;
      const f32x4 sm = g ? sum1 : sum0;
#pragma unroll
      for (int reg = 0; reg < 4; ++reg) {
        const int row = i0 + rbase + g * 16 + quad * 4 + reg;
        const float ls = __shfl(sm[reg], quad * 16);
        const float il = ls > 0.f ? 1.f / ls : 0.f;
#pragma unroll
        for (int nt = 0; nt < 4; ++nt) {
          float v = acc[nt][reg] * il;
          v = v > 0.f ? v : expm1f(v);  // elu
          const long o = (long)(p & 3) * strideB + (long)row * rowStride + (p >> 2) * 64 + nt * 16 + lm;
          out1[o] = v;
          if (out2) out2[o] = v;
        }
      }
    }
  } else {
    float* pAcc = partAcc + ((long)p * jsCount + js) * NN * 64;
    float* pSum = partSum + ((long)p * jsCount + js) * NN;
#pragma unroll
    for (int g = 0; g < 2; ++g) {
      const f32x4* acc = g ? acc1 : acc0;
      const f32x4 sm = g ? sum1 : sum0;
#pragma unroll
      for (int reg = 0; reg < 4; ++reg) {
        const int row = i0 + rbase + g * 16 + quad * 4 + reg;
#pragma unroll
        for (int nt = 0; nt < 4; ++nt) pAcc[(long)row * 64 + nt * 16 + lm] = acc[nt][reg];
        if (lm == 0) pSum[row] = sm[reg];
      }
    }
  }
}

// ---------------- combine j-split partials: normalize + elu + dual write ----------------
__global__ __launch_bounds__(256) void combine_k(const float* __restrict__ partAcc,
                                                 const float* __restrict__ partSum,
                                                 float* __restrict__ img,
                                                 float* __restrict__ out, int JS) {
  const long idx = (long)blockIdx.x * 256 + threadIdx.x;
  const int cg = idx & 15;
  const int row = (int)((idx >> 4) & (NN - 1));
  const int inst = (int)(idx >> 15);
  f32x4 v = (f32x4){0.f, 0.f, 0.f, 0.f};
  float s = 0.f;
  for (int js = 0; js < JS; ++js) {
    const long b = ((long)inst * JS + js) * NN;
    v += *(const f32x4*)(partAcc + (b + row) * 64 + cg * 4);
    s += partSum[b + row];
  }
  const float il = s > 0.f ? 1.f / s : 0.f;
  f32x4 r;
#pragma unroll
  for (int q = 0; q < 4; ++q) {
    float x = v[q] * il;
    r[q] = x > 0.f ? x : expm1f(x);
  }
  const long o = ((long)inst * NN + row) * 64 + cg * 4;
  *(f32x4*)(img + o) = r;
  *(f32x4*)(out + o) = r;
}

// ---------------- layer-3a: on-the-fly Wh3, j-split partials (grid B x 8) ----------------
__global__ __launch_bounds__(256) void layer3a_k(
    const float* __restrict__ img, const float* __restrict__ W2,
    const float* __restrict__ a2, const unsigned char* __restrict__ pm,
    float* __restrict__ pOut /* [B][8][17] */) {
  const int bb = blockIdx.x, chunk = blockIdx.y, t = threadIdx.x;
  const float* A = img + (long)bb * NN * 64;
  __shared__ float w2alo[64], w2ahi[64];
  __shared__ float W2s[64][17];
  __shared__ float redc[4][17];
  if (t < 64) {
    float sl = 0.f, sh = 0.f;
#pragma unroll
    for (int c = 0; c < 16; ++c) {
      const float wv = W2[t * 16 + c];
      W2s[t][c] = wv;
      sl += wv * a2[c];
      sh += wv * a2[16 + c];
    }
    w2alo[t] = sl;
    w2ahi[t] = sh;
  }
  __syncthreads();

  float es = 0.f;
#pragma unroll 16
  for (int k = 0; k < 64; ++k) es += A[k] * w2alo[k];

  const int j = chunk * 256 + t;
  float arow[64];
#pragma unroll
  for (int q = 0; q < 16; ++q) *(f32x4*)(arow + q * 4) = *(const f32x4*)(A + (long)j * 64 + q * 4);
  float ed = 0.f;
#pragma unroll
  for (int k = 0; k < 64; ++k) ed += arow[k] * w2ahi[k];
  float e = es + ed;
  e = fmaxf(e, 0.2f * e);
  const float pv = pm[((long)(j >> 5) << 16) + (j & 31)] ? __expf(e) : 0.f;  // row 0 mask

  float acc[16];
#pragma unroll
  for (int c = 0; c < 16; ++c) {
    float wh = 0.f;
#pragma unroll
    for (int k = 0; k < 64; ++k) wh += arow[k] * W2s[k][c];
    acc[c] = pv * wh;
  }
  float lsum = pv;

#pragma unroll
  for (int off = 32; off > 0; off >>= 1) {
    lsum += __shfl_down(lsum, off);
#pragma unroll
    for (int c = 0; c < 16; ++c) acc[c] += __shfl_down(acc[c], off);
  }
  if ((t & 63) == 0) {
    const int wv = t >> 6;
#pragma unroll
    for (int c = 0; c < 16; ++c) redc[wv][c] = acc[c];
    redc[wv][16] = lsum;
  }
  __syncthreads();
  if (t < 17) {
    pOut[((long)bb * 8 + chunk) * 17 + t] =
        redc[0][t] + redc[1][t] + redc[2][t] + redc[3][t];
  }
}

// ---------------- layer-3b: sum 8 chunks, normalize + elu ----------------
__global__ __launch_bounds__(64) void layer3b_k(const float* __restrict__ pOut,
                                                float* __restrict__ outPre) {
  const int t = threadIdx.x;
  if (t >= 64) return;
  const int bb = t >> 4, c = t & 15;
  float a = 0.f, l = 0.f;
#pragma unroll
  for (int ch = 0; ch < 8; ++ch) {
    a += pOut[((long)bb * 8 + ch) * 17 + c];
    l += pOut[((long)bb * 8 + ch) * 17 + 16];
  }
  float v = a / l;
  v = v > 0.f ? v : expm1f(v);
  outPre[bb * 16 + c] = v;
}

// ---------------- host ----------------
extern "C" void kernel_launch(void* const* d_in, const int* in_sizes, int n_in,
                              void* d_out, int out_size, void* d_ws, size_t ws_size,
                              hipStream_t stream) {
  (void)in_sizes; (void)n_in; (void)out_size; (void)ws_size;
  constexpr int B = 4, N = NN, JS2 = 4, KS2 = 4;

  const float* slices = (const float*)d_in[0];
  const int* adj = (const int*)d_in[1];
  const float* Ws = (const float*)d_in[2];
  const float* As = (const float*)d_in[3];
  const float* W1 = (const float*)d_in[4];
  const float* a1 = (const float*)d_in[5];
  const float* W2 = (const float*)d_in[6];
  const float* a2 = (const float*)d_in[7];
  float* out = (float*)d_out;

  char* w = (char*)d_ws;
  size_t off = 0;
  auto alloc = [&](size_t bytes) {
    void* ptr = w + off;
    off += (bytes + 255) & ~(size_t)255;
    return ptr;
  };
  unsigned char* pm = (unsigned char*)alloc((size_t)64 * 65536);  // 4 MB kb-tiled mask
  __bf16* WsFh = (__bf16*)alloc((size_t)8 * 128 * 64 * 2);
  __bf16* WsFl = (__bf16*)alloc((size_t)8 * 128 * 64 * 2);
  __bf16* W1Fh = (__bf16*)alloc((size_t)512 * 64 * 2);
  __bf16* W1Fl = (__bf16*)alloc((size_t)512 * 64 * 2);
  f16* WhB1 = (f16*)alloc((size_t)32 * N * 64 * 2);  // 8 MB
  float* E1 = (float*)alloc((size_t)32 * N * 4);
  float* G1 = (float*)alloc((size_t)32 * N * 4);
  f16* F1 = (f16*)alloc((size_t)32 * N * 2);
  f16* H1 = (f16*)alloc((size_t)32 * N * 2);
  float* x = (float*)alloc((size_t)B * N * 512 * 4);  // 16 MB
  float* pC2 = (float*)alloc((size_t)B * KS2 * N * 64 * 4);  // 8 MB
  f16* WhB2 = (f16*)alloc((size_t)B * N * 64 * 2);
  float* E2 = (float*)alloc((size_t)B * N * 4);
  float* G2 = (float*)alloc((size_t)B * N * 4);
  f16* F2 = (f16*)alloc((size_t)B * N * 2);
  f16* H2 = (f16*)alloc((size_t)B * N * 2);
  float* img = (float*)alloc((size_t)B * N * 64 * 4);  // 2 MB
  float* pAcc2 = (float*)alloc((size_t)B * JS2 * N * 64 * 4);  // 8 MB
  float* pSum2 = (float*)alloc((size_t)B * JS2 * N * 4);
  float* pL3 = (float*)alloc((size_t)B * 8 * 17 * 4);

  prep_k<<<dim3(2432), dim3(256), 0, stream>>>(adj, pm, Ws, WsFh, WsFl, W1, W1Fh, W1Fl);

  // layer 1
  gemm_mfma_k<<<dim3(N / 32, 32, 1), dim3(128), 0, stream>>>(
      slices, WsFh, WsFl, As, WhB1, E1, G1, F1, H1, (float*)nullptr,
      128, 1, (long)N * 128);
  attn_k<<<dim3(N / 128, 1, 32), dim3(512), 0, stream>>>(
      WhB1, E1, G1, F1, H1, pm, x, (float*)nullptr, 512, (long)N * 512,
      1, (float*)nullptr, (float*)nullptr);

  // layer 2
  gemm_mfma_k<<<dim3(N / 32, 4, KS2), dim3(128), 0, stream>>>(
      x, W1Fh, W1Fl, a1, (f16*)nullptr, (float*)nullptr, (float*)nullptr,
      (f16*)nullptr, (f16*)nullptr, pC2, 512, KS2, (long)N * 512);
  gemm_epi_k<<<dim3(N / 16, 4), dim3(256), 0, stream>>>(
      pC2, a1, WhB2, E2, G2, F2, H2, KS2);
  attn_k<<<dim3(N / 128, JS2, 4), dim3(512), 0, stream>>>(
      WhB2, E2, G2, F2, H2, pm, (float*)nullptr, (float*)nullptr, 64, (long)N * 64,
      JS2, pAcc2, pSum2);
  combine_k<<<dim3(B * N * 16 / 256), dim3(256), 0, stream>>>(pAcc2, pSum2, img, out, JS2);

  // layer 3
  layer3a_k<<<dim3(B, 8), dim3(256), 0, stream>>>(img, W2, a2, pm, pL3);
  layer3b_k<<<dim3(1), dim3(64), 0, stream>>>(pL3, out + (size_t)B * N * 64);
}